// Round 4
// baseline (50874.176 us; speedup 1.0000x reference)
//
#include <hip/hip_runtime.h>

// Fused persistent-weight LSTM, fp32 I/O, split-bf16 MFMA. MI355X (gfx950).
//
// R7 = R6 hardened (R6 never ran: harness infra failure).
//  - asm vector outputs use ext_vector_type(4) u32 (ISel-safe) instead of
//    struct uint4.
//  - fast-path flag poll gets an agent-scope mirror + bounded-spin watchdog:
//    if sc0 loads were ever L1-stale, the consumer escapes via the mirror and
//    the kernel completes correct-but-slow instead of hanging.
//  - nonce clamped to [0x40000000, 0x7FFFFFFF] so nonce+t never == 0 (memset).
//
// R5 design: XCD-local L2 h-exchange with empirical coherence probe.
//  - Chains (mg = blk&7) are expected XCD-uniform under the CP's round-robin
//    blockIdx->XCD mapping. One-time probe: each block sc0-stores a nonce-
//    tagged test line, agent-scope rendezvous, reads all 32 chain lines with
//    sc0. Any mismatch -> chain votes fallback (agent atomics, R3-style).
//    Wrong placement degrades, never hangs/corrupts.
//  - Fast path: h stored packed u32 via sc0 (write-through -> local L2,
//    ~250cy RT, zero IF traffic). Per-wave ready flags (nonce + t + 1) stored
//    after s_waitcnt vmcnt(0). Consumers poll 64 flags (1 dword/lane), then
//    16x dwordx4 sc0 h loads. No per-step counter fetch_add, no IF RTs.
//  - Structure from R4 (field-verified): wave specialization (waves 0-1 = x
//    K-half staged off critical path, waves 2-3 = h K-half), wave-private
//    swizzled LDS staging, ONE __syncthreads/step with double-buffered xchg.
//  - Slot-reuse safety: producer overwrites slot s only after passing flags
//    of step t+1, which require every consumer's step-t loads complete.
//
// Numerics unchanged: v = hi + lo (bf16 each); acc += ah*wh + al*wh + ah*wl
// in fp32 MFMA accumulators (verified absmax 2e-3 vs threshold 1.66e-2).

typedef unsigned short u16;
typedef unsigned int   u32;
typedef unsigned long long u64;
typedef short bf16x8 __attribute__((ext_vector_type(8)));
typedef float f32x4  __attribute__((ext_vector_type(4)));
typedef u32   u32x4  __attribute__((ext_vector_type(4)));

#define TT 512
#define BB 128
#define DD 512
#define HH 512

// ws layout (u32 indices):
//   [mg*32 + c]             3 rendezvous counters per chain (c = 0,1,2)
//   [256 + mg*16]           chainBad vote
//   [512 + mg*16]           launch nonce per chain
//   [1024 + (mg*32+nb)*16]  coherence test lines (64 B apart)
//   [8192  + (s*8+mg)*128 + nb*4 + wv]  sc0 ready flags
//   [12288 + (s*8+mg)*128 + nb*4 + wv]  agent mirror flags (watchdog escape)
//   [16384 ...]             hbuf: u32 [2][BB][HH] packed (hi|lo) bf16
#define WS_CNT(mg, c)    ((mg) * 32 + (c))
#define WS_BAD(mg)       (256 + (mg) * 16)
#define WS_NONCE(mg)     (512 + (mg) * 16)
#define WS_TEST(mg, nb)  (1024 + ((mg) * 32 + (nb)) * 16)
#define WS_FLAG(s, mg)   (8192 + ((s) * 8 + (mg)) * 128)
#define WS_FLAGM(s, mg)  (12288 + ((s) * 8 + (mg)) * 128)
#define WS_HBUF_U32      16384

__device__ __forceinline__ float bf2f(u16 u) { return __uint_as_float(((u32)u) << 16); }
__device__ __forceinline__ u16 f2bf(float f) {
    u32 u = __float_as_uint(f);
    return (u16)((u + 0x7FFFu + ((u >> 16) & 1u)) >> 16);   // RNE
}
__device__ __forceinline__ u32 pack2(u16 a, u16 b) { return (u32)a | ((u32)b << 16); }
__device__ __forceinline__ float sigm(float x)  { return 1.0f / (1.0f + __expf(-x)); }
__device__ __forceinline__ float tanh_(float x) { return 1.0f - 2.0f / (1.0f + __expf(2.0f * x)); }

// XCD-L2-scoped ops: bypass L1 (sc0), stay in the local L2.
__device__ __forceinline__ void st_sc0_u32(u32* p, u32 v) {
    asm volatile("global_store_dword %0, %1, off sc0" :: "v"(p), "v"(v) : "memory");
}
__device__ __forceinline__ u32 ld_sc0_u32(const u32* p) {
    u32 v;
    asm volatile("global_load_dword %0, %1, off sc0\n\ts_waitcnt vmcnt(0)"
                 : "=v"(v) : "v"(p) : "memory");
    return v;
}

__device__ __forceinline__ void rendezvous32(u32* c) {   // whole block calls; 32 blocks/chain
    __syncthreads();
    if (threadIdx.x == 0) {
        __hip_atomic_fetch_add(c, 1u, __ATOMIC_RELEASE, __HIP_MEMORY_SCOPE_AGENT);
        while (__hip_atomic_load(c, __ATOMIC_ACQUIRE, __HIP_MEMORY_SCOPE_AGENT) < 32u)
            __builtin_amdgcn_s_sleep(2);
    }
    __syncthreads();
}

__launch_bounds__(256, 1)
__global__ void lstm_fused(const float* __restrict__ x,
                           const float* __restrict__ Wf, const float* __restrict__ bfv,
                           const float* __restrict__ Wi, const float* __restrict__ biv,
                           const float* __restrict__ Wg, const float* __restrict__ bgv,
                           const float* __restrict__ Wo, const float* __restrict__ bov,
                           float* __restrict__ out, u32* __restrict__ ws)
{
    // hi plane [16 rows][1024 cols] bf16 (32 KB) then lo plane at +0x8000.
    // Within-row byte offset XOR-swizzled: off ^= (row&7)<<4.
    __shared__ __align__(16) u16   aPl[2 * 16 * 1024];
    __shared__ __align__(16) float xch[2][4 * 4 * 16 * 20];   // dbuf [wave][gate][col][row16+4]

    const int tid  = threadIdx.x;
    const int lane = tid & 63;
    const int wv   = tid >> 6;        // wave 0..3 : K-quarter owner
    const int l16  = lane & 15;
    const int quad = lane >> 4;
    const int blk  = blockIdx.x;
    const int mg   = blk & 7;         // chain id (XCD-affine under round-robin)
    const int nb   = blk >> 3;        // hidden-col slice 0..31
    const int rowbase = mg * 16;
    const int kwb  = wv * 256;
    const bool isH = (wv >= 2);       // waves 2,3 own the h K-half

    // ---- one-time: persistent split-bf16 B fragments ----
    const float* Wq[4] = { Wf, Wi, Wg, Wo };
    bf16x8 whi[4][8], wlo[4][8];
#pragma unroll
    for (int q = 0; q < 4; ++q) {
        const float* Wp = Wq[q] + (size_t)(kwb + quad * 8) * HH + nb * 16 + l16;
#pragma unroll
        for (int s = 0; s < 8; ++s)
#pragma unroll
            for (int j = 0; j < 8; ++j) {
                float wval = Wp[(size_t)(s * 32 + j) * HH];
                u16 h = f2bf(wval);
                whi[q][s][j] = (short)h;
                wlo[q][s][j] = (short)f2bf(wval - bf2f(h));
            }
    }

    // ---- elementwise mapping ----
    const int ec = tid & 15, er = tid >> 4;
    const int hcol = nb * 16 + ec;
    const float bias[4] = { bfv[hcol], biv[hcol], bgv[hcol], bov[hcol] };
    float cst = 0.0f;
    const int gidx = (rowbase + er) * HH + hcol;
    u32* hbufU = ws + WS_HBUF_U32;

    // ---- staging lane geometry (wave-private region: 16 rows x 256 cols) ----
    const int srow = isH ? (lane & 15) : (lane >> 2);
    const int scb  = isH ? (lane >> 4) : (lane & 3);

    char* aB = (char*)aPl;
    int wrA[8], rdA[8];
    {
        const int swzW = (srow & 7) << 4;
#pragma unroll
        for (int i = 0; i < 8; ++i)
            wrA[i] = srow * 2048 + wv * 512 + ((scb * 128 + i * 16) ^ swzW);
        const int swzR = (l16 & 7) << 4;
#pragma unroll
        for (int s = 0; s < 8; ++s)
            rdA[s] = l16 * 2048 + wv * 512 + ((quad * 16 + s * 64) ^ swzR);
    }

    const float* xptr = x + (size_t)(rowbase + srow) * DD + kwb + scb * 64;

    // ---- one-time coherence probe: is this chain single-L2? ----
    bool fast;
    u32 nonceV;
    {
        if (nb == 0 && tid == 0) {
            u32 nv = ((u32)__builtin_amdgcn_s_memrealtime() & 0x3FFFFFFFu) | 0x40000000u;
            __hip_atomic_store(ws + WS_NONCE(mg), nv, __ATOMIC_RELEASE, __HIP_MEMORY_SCOPE_AGENT);
        }
        rendezvous32(ws + WS_CNT(mg, 0));
        nonceV = __hip_atomic_load(ws + WS_NONCE(mg), __ATOMIC_ACQUIRE, __HIP_MEMORY_SCOPE_AGENT);
        if (tid == 0) {
            st_sc0_u32(ws + WS_TEST(mg, nb), nonceV ^ ((u32)nb * 0x9E3779B9u));
            asm volatile("s_waitcnt vmcnt(0)" ::: "memory");
        }
        rendezvous32(ws + WS_CNT(mg, 1));
        bool ok = true;
        if (tid < 32)
            ok = (ld_sc0_u32(ws + WS_TEST(mg, tid)) == (nonceV ^ ((u32)tid * 0x9E3779B9u)));
        bool allok = __all(ok);   // wave0 holds the 32 readers; other waves trivially true
        if (tid == 0 && !allok)
            __hip_atomic_fetch_or(ws + WS_BAD(mg), 1u, __ATOMIC_RELEASE, __HIP_MEMORY_SCOPE_AGENT);
        rendezvous32(ws + WS_CNT(mg, 2));
        fast = (__hip_atomic_load(ws + WS_BAD(mg), __ATOMIC_ACQUIRE, __HIP_MEMORY_SCOPE_AGENT) == 0u);
    }

    for (int t = 0; t < TT; ++t) {
        // ---- stage own K-quarter of A = [x_t | h_{t-1}] (split hi/lo) ----
        if (!isH) {
            const float4* xs = (const float4*)xptr;
#pragma unroll
            for (int g = 0; g < 8; ++g) {
                float4 a = xs[2 * g], b = xs[2 * g + 1];
                u16 h0 = f2bf(a.x), h1 = f2bf(a.y), h2 = f2bf(a.z), h3 = f2bf(a.w);
                u16 h4 = f2bf(b.x), h5 = f2bf(b.y), h6 = f2bf(b.z), h7 = f2bf(b.w);
                uint4 H = { pack2(h0, h1), pack2(h2, h3), pack2(h4, h5), pack2(h6, h7) };
                uint4 L = { pack2(f2bf(a.x - bf2f(h0)), f2bf(a.y - bf2f(h1))),
                            pack2(f2bf(a.z - bf2f(h2)), f2bf(a.w - bf2f(h3))),
                            pack2(f2bf(b.x - bf2f(h4)), f2bf(b.y - bf2f(h5))),
                            pack2(f2bf(b.z - bf2f(h6)), f2bf(b.w - bf2f(h7))) };
                *(uint4*)(aB + wrA[g]) = H;
                *(uint4*)(aB + wrA[g] + 32768) = L;
            }
            xptr += (size_t)BB * DD;
        } else if (t == 0) {
            uint4 z = { 0u, 0u, 0u, 0u };
#pragma unroll
            for (int g = 0; g < 8; ++g) {
                *(uint4*)(aB + wrA[g]) = z;
                *(uint4*)(aB + wrA[g] + 32768) = z;
            }
        } else {
            const int slot = (t - 1) & 1;
            const u32 want = nonceV + (u32)t;
            u32* fp  = ws + WS_FLAG(slot, mg)  + (wv - 2) * 64 + lane;
            u32* fpm = ws + WS_FLAGM(slot, mg) + (wv - 2) * 64 + lane;
            if (fast) {
                int spins = 0;
                for (;;) {
                    u32 fv = ld_sc0_u32(fp);
                    if (!__any(fv != want)) break;
                    if (++spins >= 1024) {   // watchdog: escape via agent mirror
                        u32 fm = __hip_atomic_load(fpm, __ATOMIC_RELAXED,
                                                   __HIP_MEMORY_SCOPE_AGENT);
                        if (!__any((int)(fm - want) < 0)) break;   // monotonic >=
                        __builtin_amdgcn_s_sleep(2);
                    }
                }
            } else {
                for (;;) {
                    u32 fv = __hip_atomic_load(fp, __ATOMIC_RELAXED, __HIP_MEMORY_SCOPE_AGENT);
                    if (!__any(fv != want)) break;
                    __builtin_amdgcn_s_sleep(2);
                }
            }
            const u32* hp = hbufU + (size_t)slot * (BB * HH)
                          + (size_t)(rowbase + srow) * HH + (wv - 2) * 256 + scb * 64;
            if (fast) {
                const u32x4* hp4 = (const u32x4*)hp;
                u32x4 hv4[16];
                // issue all 16 sc0 loads, then ONE standalone waitcnt.
#pragma unroll
                for (int i = 0; i < 16; ++i)
                    asm volatile("global_load_dwordx4 %0, %1, off sc0"
                                 : "=v"(hv4[i]) : "v"(hp4 + i) : "memory");
                asm volatile("s_waitcnt vmcnt(0)" ::: "memory");
                __builtin_amdgcn_sched_barrier(0);   // keep unpack below the wait (rule #18)
#pragma unroll
                for (int g = 0; g < 8; ++g) {
                    u32x4 A = hv4[2 * g], B = hv4[2 * g + 1];
                    uint4 H = { (A[0] & 0xFFFFu) | (A[1] << 16), (A[2] & 0xFFFFu) | (A[3] << 16),
                                (B[0] & 0xFFFFu) | (B[1] << 16), (B[2] & 0xFFFFu) | (B[3] << 16) };
                    uint4 L = { (A[0] >> 16) | (A[1] & 0xFFFF0000u), (A[2] >> 16) | (A[3] & 0xFFFF0000u),
                                (B[0] >> 16) | (B[1] & 0xFFFF0000u), (B[2] >> 16) | (B[3] & 0xFFFF0000u) };
                    *(uint4*)(aB + wrA[g]) = H;
                    *(uint4*)(aB + wrA[g] + 32768) = L;
                }
            } else {
                const u64* hp64 = (const u64*)hp;
                u64 v64[32];
#pragma unroll
                for (int j = 0; j < 32; ++j)
                    v64[j] = __hip_atomic_load(hp64 + j, __ATOMIC_RELAXED, __HIP_MEMORY_SCOPE_AGENT);
#pragma unroll
                for (int g = 0; g < 8; ++g) {
                    u32 p0 = (u32)v64[4*g+0], p1 = (u32)(v64[4*g+0] >> 32);
                    u32 p2 = (u32)v64[4*g+1], p3 = (u32)(v64[4*g+1] >> 32);
                    u32 p4 = (u32)v64[4*g+2], p5 = (u32)(v64[4*g+2] >> 32);
                    u32 p6 = (u32)v64[4*g+3], p7 = (u32)(v64[4*g+3] >> 32);
                    uint4 H = { (p0 & 0xFFFFu) | (p1 << 16), (p2 & 0xFFFFu) | (p3 << 16),
                                (p4 & 0xFFFFu) | (p5 << 16), (p6 & 0xFFFFu) | (p7 << 16) };
                    uint4 L = { (p0 >> 16) | (p1 & 0xFFFF0000u), (p2 >> 16) | (p3 & 0xFFFF0000u),
                                (p4 >> 16) | (p5 & 0xFFFF0000u), (p6 >> 16) | (p7 & 0xFFFF0000u) };
                    *(uint4*)(aB + wrA[g]) = H;
                    *(uint4*)(aB + wrA[g] + 32768) = L;
                }
            }
        }

        // ---- MFMA: own K-quarter (wave-private LDS; no barrier needed) ----
        f32x4 acc[4];
#pragma unroll
        for (int q = 0; q < 4; ++q) acc[q] = (f32x4){0.f, 0.f, 0.f, 0.f};
#pragma unroll
        for (int s = 0; s < 8; ++s) {
            bf16x8 ah = *(const bf16x8*)(aB + rdA[s]);
            bf16x8 al = *(const bf16x8*)(aB + rdA[s] + 32768);
#pragma unroll
            for (int q = 0; q < 4; ++q) {
                acc[q] = __builtin_amdgcn_mfma_f32_16x16x32_bf16(ah, whi[q][s], acc[q], 0, 0, 0);
                acc[q] = __builtin_amdgcn_mfma_f32_16x16x32_bf16(al, whi[q][s], acc[q], 0, 0, 0);
                acc[q] = __builtin_amdgcn_mfma_f32_16x16x32_bf16(ah, wlo[q][s], acc[q], 0, 0, 0);
            }
        }
        float* xc = xch[t & 1];
#pragma unroll
        for (int q = 0; q < 4; ++q)
            *(f32x4*)&xc[((wv * 4 + q) * 16 + l16) * 20 + quad * 4] = acc[q];
        __syncthreads();              // the ONLY barrier per step

        // ---- gates ----
        float pre[4];
#pragma unroll
        for (int q = 0; q < 4; ++q) {
            float p = bias[q];
#pragma unroll
            for (int ww = 0; ww < 4; ++ww) p += xc[((ww * 4 + q) * 16 + ec) * 20 + er];
            pre[q] = p;
        }
        float fg = sigm(pre[0]);
        float ig = sigm(pre[1]);
        float gg = tanh_(pre[2]);
        float og = sigm(pre[3]);
        cst = fg * cst + ig * gg;
        float hv = og * tanh_(cst);

        // h first (critical path), then out
        u16 hh = f2bf(hv);
        u16 hl = f2bf(hv - bf2f(hh));
        u32 hpk = pack2(hh, hl);
        u32* hq = hbufU + (size_t)(t & 1) * (BB * HH) + gidx;
        if (fast) st_sc0_u32(hq, hpk);
        else __hip_atomic_store(hq, hpk, __ATOMIC_RELAXED, __HIP_MEMORY_SCOPE_AGENT);

        out[(size_t)t * (BB * HH) + gidx] = hv;
        if (t == TT - 1) {
            out[(size_t)TT * (BB * HH) + gidx] = hv;                  // hx
            out[(size_t)TT * (BB * HH) + BB * HH + gidx] = cst;       // cx
        }

        // per-wave ready flag after this wave's h stores are L2/IF-acked.
        asm volatile("s_waitcnt vmcnt(0)" ::: "memory");
        if (lane == 0) {
            u32 val = nonceV + (u32)(t + 1);
            if (fast) {
                st_sc0_u32(ws + WS_FLAG(t & 1, mg) + nb * 4 + wv, val);
                __hip_atomic_store(ws + WS_FLAGM(t & 1, mg) + nb * 4 + wv, val,
                                   __ATOMIC_RELAXED, __HIP_MEMORY_SCOPE_AGENT);
            } else {
                __hip_atomic_store(ws + WS_FLAG(t & 1, mg) + nb * 4 + wv, val,
                                   __ATOMIC_RELEASE, __HIP_MEMORY_SCOPE_AGENT);
            }
        }
        // no trailing barrier: staging is wave-private, xchg is double-buffered,
        // and the t+1 flag poll is the inter-block sync.
    }
}

extern "C" void kernel_launch(void* const* d_in, const int* in_sizes, int n_in,
                              void* d_out, int out_size, void* d_ws, size_t ws_size,
                              hipStream_t stream) {
    (void)in_sizes; (void)n_in; (void)out_size; (void)ws_size;
    const float* x   = (const float*)d_in[0];
    const float* Wf  = (const float*)d_in[1];
    const float* bfv = (const float*)d_in[2];
    const float* Wi  = (const float*)d_in[3];
    const float* biv = (const float*)d_in[4];
    const float* Wg  = (const float*)d_in[5];
    const float* bgv = (const float*)d_in[6];
    const float* Wo  = (const float*)d_in[7];
    const float* bov = (const float*)d_in[8];

    // Clear control region (counters/votes/nonces/test/flags/mirrors). hbuf
    // (at +64 KiB) needs no clearing: every read is flag-gated, flags cleared.
    (void)hipMemsetAsync(d_ws, 0, 65536, stream);
    lstm_fused<<<dim3(256), dim3(256), 0, stream>>>(x, Wf, bfv, Wi, biv, Wg, bgv, Wo, bov,
                                                    (float*)d_out, (u32*)d_ws);
}